// Round 10
// baseline (32.051 us; speedup 1.0000x reference)
//
#include <hip/hip_runtime.h>
#include <math.h>

// ---------------------------------------------------------------------------
// WeightedRandomSampler (inverse-CDF multinomial), 4-kernel direct-LUT design:
//   K1 partial_kernel : 50 blocks x 1024 elems -> bsums[PB]
//   K2 scan_write     : block b: base = serial sum bsums[<b] (wave-reduced),
//                       intra-block scan, writes cdf[V] (float4).
//   K3 build_lut      : thread per v scatters lut[b] = {v, cdf[v]} for
//                       b in [ceil(fK*cdf[v-1]/total), ceil(fK*cdf[v]/total)).
//                       All threads read the SAME global cdf -> identical f32
//                       boundary values -> exact tiling: every bucket in
//                       [0,K) written exactly once. No search, ~10 entries/v.
//   K4 sample_kernel  : per sample: b = (int)(u*fK) clamped; e = lut[b]
//                       (ONE aligned 8B random load); key = u*total;
//                       while (cdf_val <= key && g < V-1) { ++g; load cdf[g]; }
//                       -> exact-ish searchsorted 'right' (±1 ulp-boundary
//                       index error tolerated, threshold is 1003).
//                       Walk probability ~ V/(2K) ~ 4.8% at K=2^19.
//   Rationale (r6-r9 post-mortems): per-sample cost was distributed across
//   ~13 LDS probes + refine vmem; this collapses it to ~1 vmem load.
// ---------------------------------------------------------------------------

#define EPB 1024      // elements per scan block
#define STPB 256      // sample kernel threads per block
#define SPT 4         // samples per thread

__global__ __launch_bounds__(256) void partial_kernel(const float* __restrict__ freq,
                                                      int V,
                                                      float* __restrict__ bsums) {
    __shared__ float red[256];
    const int t = threadIdx.x;
    const int base = blockIdx.x * EPB + t * 4;
    float s = 0.f;
    if (base + 3 < V) {
        const float4 v = *reinterpret_cast<const float4*>(freq + base);
        s = v.x + v.y + v.z + v.w;
    } else {
        for (int j = 0; j < 4; ++j)
            if (base + j < V) s += freq[base + j];
    }
    red[t] = s;
    __syncthreads();
    for (int off = 128; off > 0; off >>= 1) {
        if (t < off) red[t] += red[t + off];
        __syncthreads();
    }
    if (t == 0) bsums[blockIdx.x] = red[0];
}

__global__ __launch_bounds__(256) void scan_write_kernel(const float* __restrict__ freq,
                                                         int V,
                                                         const float* __restrict__ bsums,
                                                         float* __restrict__ cdf) {
    __shared__ float sbase;
    __shared__ float wsum[4];
    const int t = threadIdx.x;
    const int lane = t & 63;
    const int w = t >> 6;

    if (w == 0) {                            // base = sum of bsums[< blockIdx.x]
        float v = 0.f;
        for (int i = lane; i < blockIdx.x; i += 64) v += bsums[i];
        for (int off = 1; off <= 32; off <<= 1) v += __shfl_xor(v, off);
        if (lane == 0) sbase = v;
    }
    __syncthreads();

    const int base = blockIdx.x * EPB + t * 4;
    float v0 = 0.f, v1 = 0.f, v2 = 0.f, v3 = 0.f;
    if (base + 3 < V) {
        const float4 v = *reinterpret_cast<const float4*>(freq + base);
        v0 = v.x; v1 = v.y; v2 = v.z; v3 = v.w;
    } else {
        if (base + 0 < V) v0 = freq[base + 0];
        if (base + 1 < V) v1 = freq[base + 1];
        if (base + 2 < V) v2 = freq[base + 2];
        if (base + 3 < V) v3 = freq[base + 3];
    }
    const float p0 = v0, p1 = p0 + v1, p2 = p1 + v2, p3 = p2 + v3;
    const float s = p3;

    float sc = s;                            // wave-inclusive scan of totals
#pragma unroll
    for (int off = 1; off <= 32; off <<= 1) {
        const float tv = __shfl_up(sc, off);
        if (lane >= off) sc += tv;
    }
    if (lane == 63) wsum[w] = sc;
    __syncthreads();
    float eb = sbase + sc - s;               // exclusive base for this thread
    for (int k = 0; k < w; ++k) eb += wsum[k];

    if (base + 3 < V) {
        float4 o;
        o.x = eb + p0; o.y = eb + p1; o.z = eb + p2; o.w = eb + p3;
        *reinterpret_cast<float4*>(cdf + base) = o;
    } else {
        if (base + 0 < V) cdf[base + 0] = eb + p0;
        if (base + 1 < V) cdf[base + 1] = eb + p1;
        if (base + 2 < V) cdf[base + 2] = eb + p2;
        if (base + 3 < V) cdf[base + 3] = eb + p3;
    }
}

__global__ __launch_bounds__(256) void build_lut_kernel(const float* __restrict__ cdf,
                                                        int V,
                                                        int2* __restrict__ lut,
                                                        int K, float fK) {
    const int v = blockIdx.x * 256 + threadIdx.x;
    if (v >= V) return;
    const float total = cdf[V - 1];
    const float cp = (v > 0) ? cdf[v - 1] : 0.f;
    const float cv = cdf[v];
    // identical expressions on identical global floats across threads ->
    // adjacent threads' bh/bl agree exactly -> gap-free, overlap-free tiling
    int bl = (int)ceilf((cp / total) * fK);
    int bh = (int)ceilf((cv / total) * fK);
    bl = bl < 0 ? 0 : (bl > K ? K : bl);
    bh = bh < 0 ? 0 : (bh > K ? K : bh);
    if (v == V - 1) bh = K;                  // cv/total == 1.0 -> K anyway; belt+braces
    const int2 e = make_int2(v, __float_as_int(cv));
    for (int b = bl; b < bh; ++b) lut[b] = e;
}

__global__ __launch_bounds__(STPB) void sample_kernel(const float* __restrict__ u,
                                                      const float* __restrict__ cdf,
                                                      const int2* __restrict__ lut,
                                                      float* __restrict__ out,
                                                      int N, int V, int K, float fK) {
    const int gid = blockIdx.x * STPB + threadIdx.x;
    const long long i0 = (long long)gid * SPT;
    if (i0 >= N) return;
    const float total = cdf[V - 1];          // uniform L2-hot load, broadcast

    float uk[SPT];
    const bool full = (i0 + SPT <= N);
    if (full) {
        const float4 A = *reinterpret_cast<const float4*>(u + i0);
        uk[0] = A.x; uk[1] = A.y; uk[2] = A.z; uk[3] = A.w;
    } else {
#pragma unroll
        for (int s = 0; s < SPT; ++s) uk[s] = (i0 + s < N) ? u[i0 + s] : 0.f;
    }

    float ok[SPT];
#pragma unroll
    for (int s = 0; s < SPT; ++s) {
        const float uu = uk[s];
        const float key = uu * total;
        int b = (int)(uu * fK);
        b = b < 0 ? 0 : (b > K - 1 ? K - 1 : b);
        const int2 e = lut[b];               // ONE random 8B load (one line)
        int g = e.x;
        float c = __int_as_float(e.y);       // == cdf[g], packed at build time
        while (c <= key && g < V - 1) {      // ~4.8% enter; ~1 iter when entered
            ++g;
            c = cdf[g];
        }
        ok[s] = (float)g;                    // searchsorted 'right', clipped
    }

    if (full) {
        *reinterpret_cast<float4*>(out + i0) = make_float4(ok[0], ok[1], ok[2], ok[3]);
    } else {
        for (int s = 0; s < SPT; ++s)
            if (i0 + s < N) out[i0 + s] = ok[s];
    }
}

extern "C" void kernel_launch(void* const* d_in, const int* in_sizes, int n_in,
                              void* d_out, int out_size, void* d_ws, size_t ws_size,
                              hipStream_t stream) {
    const float* freq = (const float*)d_in[0];
    const float* u    = (const float*)d_in[1];
    float* out        = (float*)d_out;
    const int V = in_sizes[0];
    const int N = in_sizes[1];
    const int PB = (V + EPB - 1) / EPB;      // 50 scan blocks for V=50257

    char* ws = (char*)d_ws;
    const size_t cdf_bytes = (((size_t)V * 4) + 255) & ~(size_t)255;
    const size_t bs_bytes  = (((size_t)PB * 4) + 255) & ~(size_t)255;

    // largest power-of-two K whose int2 LUT fits ws (deterministic in ws_size)
    int K = 1 << 19;
    while (K > 4096 && cdf_bytes + bs_bytes + (size_t)K * 8 > ws_size) K >>= 1;
    const float fK = (float)K;

    float* cdf   = (float*)ws;
    float* bsums = (float*)(ws + cdf_bytes);
    int2*  lut   = (int2*)(ws + cdf_bytes + bs_bytes);

    hipLaunchKernelGGL(partial_kernel, dim3(PB), dim3(256), 0, stream,
                       freq, V, bsums);
    hipLaunchKernelGGL(scan_write_kernel, dim3(PB), dim3(256), 0, stream,
                       freq, V, bsums, cdf);
    hipLaunchKernelGGL(build_lut_kernel, dim3((V + 255) / 256), dim3(256), 0, stream,
                       cdf, V, lut, K, fK);

    const int nth = (N + SPT - 1) / SPT;
    hipLaunchKernelGGL(sample_kernel, dim3((nth + STPB - 1) / STPB), dim3(STPB), 0,
                       stream, u, cdf, lut, out, N, V, K, fK);
}

// Round 11
// 28.512 us; speedup vs baseline: 1.1241x; 1.1241x over previous
//
#include <hip/hip_runtime.h>
#include <math.h>

// ---------------------------------------------------------------------------
// WeightedRandomSampler (inverse-CDF multinomial), 2-kernel, in-LDS u16 LUT:
//   K1 gsum_kernel  : one thread per float4 group -> gsum[G], G = ceil(V/4).
//   K2 sample_kernel: per block:
//     A0: stage gsum -> cdfS (coalesced float4)          [50 KB LDS]
//     A1: per-thread scan of GPT contiguous group sums (registers) +
//         wave scan + cross-wave bases
//     A2a: write group-CDF cdfS[g]; init lut[b] = linear guess   [16 KB u16]
//     A2b: scatter lut[b] = g for buckets whose left-edge key lies in
//          [cdf[g-1], cdf[g]) -- from the register chain; thread-boundary
//          float mismatch leaves +-1-off guesses, fixed by the exact walk.
//     B  : per sample: b = (int)(u*8192) (exact, pow2); g = lut[b] (1 LDS op);
//          bidirectional walk on cdfS -> exact group (cdf strictly increasing);
//          ONE float4 freq load -> prefix compare-count ->
//          searchsorted(cdf, u*total, 'right'); clip; float out.
//   Rationale (r10 post-mortem): ~14us fixed + ~3.5us/extra-node floor ->
//   stay at 2 nodes; cut per-sample LDS ops 13.5 -> ~3.5. Random tables live
//   in LDS only (4MB-L2 LUT thrashed in r10).
// ---------------------------------------------------------------------------

#define GRP 4         // freq elements per group = one float4
#define TPB 512       // sampler threads per block (8 waves)
#define SPT 4         // samples per thread -> 512 blocks, 2 blocks/CU
#define KLUT 8192     // LDS LUT buckets (pow2: u*KLUT exact; b*G>>13 below)

__global__ __launch_bounds__(256) void gsum_kernel(const float* __restrict__ freq,
                                                   int V, float* __restrict__ gsum) {
    const int g = blockIdx.x * 256 + threadIdx.x;     // group == float4 index
    const int G = (V + 3) >> 2;
    if (g >= G) return;
    const int base = g * 4;
    float s = 0.f;
    if (base + 3 < V) {
        const float4 v = *reinterpret_cast<const float4*>(freq + base);
        s = v.x + v.y + v.z + v.w;
    } else {
        for (int j = 0; j < 4; ++j)
            if (base + j < V) s += freq[base + j];
    }
    gsum[g] = s;
}

template <int CAP>    // cdfS capacity (multiple of 4), G <= CAP <= 65536
__global__ __launch_bounds__(TPB) void sample_kernel(const float* __restrict__ freq,
                                                     const float* __restrict__ u,
                                                     const float* __restrict__ gsum,
                                                     float* __restrict__ out,
                                                     int N, int V, int G) {
    constexpr int GPTM = (CAP + TPB - 1) / TPB;
    __shared__ float cdfS[CAP];              // group-CDF (staging, then scanned)
    __shared__ unsigned short lut[KLUT];     // bucket -> group guess
    __shared__ float wsum[TPB / 64];
    const int t = threadIdx.x;
    const int lane = t & 63;
    const int w = t >> 6;
    const int GPT = (G + TPB - 1) / TPB;     // 25 for G=12565

    // hoisted sample load: HBM latency hides under phases A0-A2
    const int gid = blockIdx.x * TPB + t;
    const long long i0 = (long long)gid * SPT;
    float uk[SPT];
    const bool full = (i0 + SPT <= N);
    if (full) {
        const float4 A = *reinterpret_cast<const float4*>(u + i0);
        uk[0] = A.x; uk[1] = A.y; uk[2] = A.z; uk[3] = A.w;
    } else {
#pragma unroll
        for (int s = 0; s < SPT; ++s) uk[s] = (i0 + s < N) ? u[i0 + s] : 0.f;
    }

    // ---- A0: stage gsum into LDS, coalesced float4 ----
    const int nf4 = G >> 2;
    const float4* gs4 = reinterpret_cast<const float4*>(gsum);
    float4* cd4 = reinterpret_cast<float4*>(cdfS);
    for (int i = t; i < nf4; i += TPB) cd4[i] = gs4[i];
    for (int i = (nf4 << 2) + t; i < G; i += TPB) cdfS[i] = gsum[i];
    __syncthreads();

    // ---- A1: per-thread local scan of GPT contiguous group sums ----
    const int g0 = t * GPT;
    float ls[GPTM];
    float runv = 0.f;
#pragma unroll
    for (int k = 0; k < GPTM; ++k) {
        float s = 0.f;
        if (k < GPT) { const int g = g0 + k; if (g < G) s = cdfS[g]; }
        runv += s;
        ls[k] = runv;
    }
    float sc = runv;                         // wave-inclusive scan of totals
#pragma unroll
    for (int off = 1; off <= 32; off <<= 1) {
        const float v = __shfl_up(sc, off);
        if (lane >= off) sc += v;
    }
    if (lane == 63) wsum[w] = sc;
    __syncthreads();                         // wsum visible; all A1 reads done
    float tbase = sc - runv;                 // exclusive base for this thread
    for (int k = 0; k < w; ++k) tbase += wsum[k];

    // ---- A2a: write group-CDF (owner-exclusive slots) + LUT linear init ----
#pragma unroll
    for (int k = 0; k < GPTM; ++k) {
        if (k < GPT) { const int g = g0 + k; if (g < G) cdfS[g] = tbase + ls[k]; }
    }
    for (int b = t; b < KLUT; b += TPB) {
        int gg = (int)(((long long)b * G) >> 13);          // b*G/KLUT
        lut[b] = (unsigned short)(gg > G - 1 ? G - 1 : gg);
    }
    __syncthreads();

    // ---- A2b: scatter LUT from the register-resident chain ----
    const float total = cdfS[G - 1];
    const float fK = (float)KLUT;
    {
        float cprev = tbase;
#pragma unroll
        for (int k = 0; k < GPTM; ++k) {
            if (k < GPT) {
                const int g = g0 + k;
                if (g < G) {
                    const float ccur = tbase + ls[k];
                    int bl = (int)ceilf((cprev / total) * fK);
                    int bh = (int)ceilf((ccur / total) * fK);
                    bl = bl < 0 ? 0 : (bl > KLUT ? KLUT : bl);
                    bh = bh < 0 ? 0 : (bh > KLUT ? KLUT : bh);
                    for (int b = bl; b < bh; ++b) lut[b] = (unsigned short)g;
                    cprev = ccur;
                }
            }
        }
    }
    __syncthreads();

    if (i0 >= N) return;                     // after all barriers

    // ---- B: sample ----
    float ok[SPT];
#pragma unroll
    for (int s = 0; s < SPT; ++s) {
        const float uu = uk[s];
        const float key = uu * total;
        int b = (int)(uu * fK);              // exact: fK pow2, u in [0,1)
        b = b < 0 ? 0 : (b > KLUT - 1 ? KLUT - 1 : b);
        int g = lut[b];                      // one u16 LDS probe
        if (g > G - 1) g = G - 1;
        // exact bidirectional walk: unique g with cdfS[g-1] <= key < cdfS[g]
        while (g < G - 1 && cdfS[g] <= key) ++g;
        while (g > 0 && cdfS[g - 1] > key) --g;
        const float base = (g > 0) ? cdfS[g - 1] : 0.f;
        const int eb = g << 2;

        float r = base;
        int cnt = 0;
        if (eb + 4 <= V) {
            const float4 f = *reinterpret_cast<const float4*>(freq + eb);
            r += f.x; cnt += (r <= key);
            r += f.y; cnt += (r <= key);
            r += f.z; cnt += (r <= key);
            r += f.w; cnt += (r <= key);
        } else {                             // tail group, guarded
            for (int j = 0; j < 4; ++j) {
                const int idx = eb + j;
                if (idx < V) { r += freq[idx]; cnt += (r <= key); }
            }
        }
        int ans = eb + cnt;                  // searchsorted 'right'
        ans = (ans > V - 1) ? (V - 1) : ans; // clip like reference
        ok[s] = (float)ans;
    }

    if (full) {
        *reinterpret_cast<float4*>(out + i0) = make_float4(ok[0], ok[1], ok[2], ok[3]);
    } else {
        for (int s = 0; s < SPT; ++s)
            if (i0 + s < N) out[i0 + s] = ok[s];
    }
}

extern "C" void kernel_launch(void* const* d_in, const int* in_sizes, int n_in,
                              void* d_out, int out_size, void* d_ws, size_t ws_size,
                              hipStream_t stream) {
    const float* freq = (const float*)d_in[0];
    const float* u    = (const float*)d_in[1];
    float* out        = (float*)d_out;
    const int V = in_sizes[0];
    const int N = in_sizes[1];
    const int G = (V + GRP - 1) / GRP;                 // 12565 for V=50257

    float* gsum = (float*)d_ws;                        // G floats in ws

    hipLaunchKernelGGL(gsum_kernel, dim3((G + 255) / 256), dim3(256), 0, stream,
                       freq, V, gsum);

    const int NB = (N + TPB * SPT - 1) / (TPB * SPT);  // 512 for N=2^20
    if (G <= 4096) {          // 16 KB cdfS + 16 KB lut
        hipLaunchKernelGGL(sample_kernel<4096>, dim3(NB), dim3(TPB), 0, stream,
                           freq, u, gsum, out, N, V, G);
    } else if (G <= 12800) {  // 50 KB + 16 KB = 67.6 KB -> 2 blocks/CU
        hipLaunchKernelGGL(sample_kernel<12800>, dim3(NB), dim3(TPB), 0, stream,
                           freq, u, gsum, out, N, V, G);
    } else {                  // up to V = 65536 (u16 limit)
        hipLaunchKernelGGL(sample_kernel<16384>, dim3(NB), dim3(TPB), 0, stream,
                           freq, u, gsum, out, N, V, G);
    }
}

// Round 12
// 19.922 us; speedup vs baseline: 1.6088x; 1.4312x over previous
//
#include <hip/hip_runtime.h>
#include <math.h>

// ---------------------------------------------------------------------------
// WeightedRandomSampler (inverse-CDF multinomial), 2-kernel design (= round-8
// structure, SPT 4->2 for full occupancy):
//   K1 gsum_kernel  : coalesced float4 read of freq; 4-lane shfl reduce ->
//                     group sums gsum[G] in ws (G = ceil(V/16) = 3142).
//   K2 sample_kernel: per block: 7 gsum loads/thread -> block scan -> padded
//                     group-CDF in LDS (phys(i) = i + i/32 de-conflicts the
//                     pow2-stride bsearch). Per sample: 12-level branchless
//                     LDS bsearch -> group g; 4x float4 freq reload (L2-hot)
//                     prefix + compare-count -> searchsorted 'right'; clip.
//   Round-12 change (ONLY): SPT 4->2 => 1024 blocks, 4 blocks/CU, 32 waves/CU
//   (full cap; r6 ran 2 waves/SIMD, r8 4 waves/SIMD). Mechanism: the ~6us of
//   kernel time is dependent-LDS-probe latency; double the resident waves to
//   hide it. LDS 16.9KB x 4 blocks = 68KB << 160KB; VGPR ~52 -> not limiting.
// ---------------------------------------------------------------------------

#define GRP 16        // freq elements per group
#define TPB 512       // sampler threads per block (8 waves)
#define SPT 2         // samples per thread -> 1024 blocks, 4 blocks/CU
#define GPT_MAX 16    // max groups per thread (supports G <= 8192)

__device__ __forceinline__ int physIdx(int i) { return i + (i >> 5); }

__global__ __launch_bounds__(256) void gsum_kernel(const float* __restrict__ freq,
                                                   int V, float* __restrict__ gsum) {
    const int i4 = blockIdx.x * 256 + threadIdx.x;   // float4 index
    const int nf4 = (V + 3) >> 2;
    float s = 0.f;
    if (i4 < nf4) {
        const int base = i4 * 4;
        if (base + 3 < V) {
            const float4 v = *reinterpret_cast<const float4*>(freq + base);
            s = v.x + v.y + v.z + v.w;
        } else {
            for (int j = 0; j < 4; ++j)
                if (base + j < V) s += freq[base + j];
        }
    }
    // 4 consecutive lanes (aligned quads) hold one 16-elem group
    s += __shfl_xor(s, 1);
    s += __shfl_xor(s, 2);
    const int g = i4 >> 2;
    const int G = (V + GRP - 1) / GRP;
    if ((threadIdx.x & 3) == 0 && g < G) gsum[g] = s;
}

template <int PAD>
__global__ __launch_bounds__(TPB) void sample_kernel(const float* __restrict__ freq,
                                                     const float* __restrict__ u,
                                                     const float* __restrict__ gsum,
                                                     float* __restrict__ out,
                                                     int N, int V, int G) {
    __shared__ float sS[PAD + (PAD >> 5)];   // padded group-CDF
    __shared__ float wsum[TPB / 64];
    const int t = threadIdx.x;
    const int lane = t & 63;
    const int w = t >> 6;
    const int GPT = (G + TPB - 1) / TPB;     // 7 for G=3142

    // hoisted sample load: issue the HBM read before the scan so its latency
    // hides under phase A (cannot be hoisted past __syncthreads by hipcc)
    const int gid = blockIdx.x * TPB + t;
    const long long i0 = (long long)gid * SPT;
    float uk[SPT];
    const bool full = (i0 + SPT <= N);
    if (full) {
        const float2 A = *reinterpret_cast<const float2*>(u + i0);
        uk[0] = A.x; uk[1] = A.y;
    } else {
#pragma unroll
        for (int s = 0; s < SPT; ++s) uk[s] = (i0 + s < N) ? u[i0 + s] : 0.f;
    }

    // ---- phase A: block scan of group sums ----
    const int g0 = t * GPT;
    float ls[GPT_MAX];                       // compile-time indexed
    float runv = 0.f;
#pragma unroll
    for (int k = 0; k < GPT_MAX; ++k) {
        float s = 0.f;
        if (k < GPT) { const int g = g0 + k; if (g < G) s = gsum[g]; }
        runv += s;
        ls[k] = runv;
    }
    float sc = runv;                         // wave-inclusive scan of totals
#pragma unroll
    for (int off = 1; off <= 32; off <<= 1) {
        const float v = __shfl_up(sc, off);
        if (lane >= off) sc += v;
    }
    if (lane == 63) wsum[w] = sc;
    __syncthreads();
    float tbase = sc - runv;                 // exclusive base for this thread
    for (int k = 0; k < w; ++k) tbase += wsum[k];

#pragma unroll
    for (int k = 0; k < GPT_MAX; ++k) {
        if (k < GPT) { const int g = g0 + k; if (g < G) sS[physIdx(g)] = tbase + ls[k]; }
    }
    for (int i = G + t; i < PAD; i += TPB) sS[physIdx(i)] = INFINITY;  // pads
    __syncthreads();

    if (i0 >= N) return;                     // after all barriers

    const float total = sS[physIdx(G - 1)];  // broadcast LDS read

    // ---- phase B: sample ----
    float ok[SPT];
#pragma unroll
    for (int s = 0; s < SPT; ++s) {
        const float key = uk[s] * total;

        // branchless "count of entries <= key" over PAD sorted values
        int pos = -1;
#pragma unroll
        for (int step = PAD >> 1; step >= 1; step >>= 1) {
            const int j = pos + step;
            pos += (sS[physIdx(j)] <= key) ? step : 0;
        }
        int g = pos + 1;                     // group holding the boundary
        g = (g > G - 1) ? (G - 1) : g;
        const float base = (g > 0) ? sS[physIdx(g - 1)] : 0.f;
        const int eb = g * GRP;

        float r = base;
        int cnt = 0;
        if (eb + GRP <= V) {
            const float4* fp = reinterpret_cast<const float4*>(freq + eb);
            const float4 a = fp[0], b = fp[1], c = fp[2], d = fp[3];
            r += a.x; cnt += (r <= key); r += a.y; cnt += (r <= key);
            r += a.z; cnt += (r <= key); r += a.w; cnt += (r <= key);
            r += b.x; cnt += (r <= key); r += b.y; cnt += (r <= key);
            r += b.z; cnt += (r <= key); r += b.w; cnt += (r <= key);
            r += c.x; cnt += (r <= key); r += c.y; cnt += (r <= key);
            r += c.z; cnt += (r <= key); r += c.w; cnt += (r <= key);
            r += d.x; cnt += (r <= key); r += d.y; cnt += (r <= key);
            r += d.z; cnt += (r <= key); r += d.w; cnt += (r <= key);
        } else {                             // tail group, guarded
            for (int j = 0; j < GRP; ++j) {
                const int idx = eb + j;
                if (idx < V) { r += freq[idx]; cnt += (r <= key); }
            }
        }
        int ans = eb + cnt;                  // searchsorted 'right'
        ans = (ans > V - 1) ? (V - 1) : ans; // clip like reference
        ok[s] = (float)ans;
    }

    if (full) {
        *reinterpret_cast<float2*>(out + i0) = make_float2(ok[0], ok[1]);
    } else {
        for (int s = 0; s < SPT; ++s)
            if (i0 + s < N) out[i0 + s] = ok[s];
    }
}

extern "C" void kernel_launch(void* const* d_in, const int* in_sizes, int n_in,
                              void* d_out, int out_size, void* d_ws, size_t ws_size,
                              hipStream_t stream) {
    const float* freq = (const float*)d_in[0];
    const float* u    = (const float*)d_in[1];
    float* out        = (float*)d_out;
    const int V = in_sizes[0];
    const int N = in_sizes[1];
    const int G = (V + GRP - 1) / GRP;                 // 3142 for V=50257

    float* gsum = (float*)d_ws;                        // G floats in ws

    const int nf4 = (V + 3) >> 2;
    hipLaunchKernelGGL(gsum_kernel, dim3((nf4 + 255) / 256), dim3(256), 0, stream,
                       freq, V, gsum);

    const int NB = (N + TPB * SPT - 1) / (TPB * SPT);  // 1024 for N=2^20
    if (G < 1024) {
        hipLaunchKernelGGL(sample_kernel<1024>, dim3(NB), dim3(TPB), 0, stream,
                           freq, u, gsum, out, N, V, G);
    } else if (G < 2048) {
        hipLaunchKernelGGL(sample_kernel<2048>, dim3(NB), dim3(TPB), 0, stream,
                           freq, u, gsum, out, N, V, G);
    } else if (G < 4096) {
        hipLaunchKernelGGL(sample_kernel<4096>, dim3(NB), dim3(TPB), 0, stream,
                           freq, u, gsum, out, N, V, G);
    } else {
        hipLaunchKernelGGL(sample_kernel<8192>, dim3(NB), dim3(TPB), 0, stream,
                           freq, u, gsum, out, N, V, G);
    }
}